// Round 7
// baseline (103.941 us; speedup 1.0000x reference)
//
#include <hip/hip_runtime.h>

typedef unsigned short u16;
typedef u16 u16x8 __attribute__((ext_vector_type(8)));
typedef __bf16 bf16x8 __attribute__((ext_vector_type(8)));
typedef float f32x4 __attribute__((ext_vector_type(4)));

#define MFMA16 __builtin_amdgcn_mfma_f32_16x16x32_bf16

__device__ __forceinline__ u16 f2bf(float f) {
  unsigned u = __builtin_bit_cast(unsigned, f);
  u += 0x7FFFu + ((u >> 16) & 1u);
  return (u16)(u >> 16);
}

// XOR-swizzled LDS byte address for 64-bf16 (128B) rows (guide G4).
__device__ __forceinline__ int swz(int row, int bcol) {
  return row * 128 + (bcol ^ ((row & 7) << 4));
}

__device__ __forceinline__ void gl16(const u16* g, u16* l) {
  __builtin_amdgcn_global_load_lds(
      (const __attribute__((address_space(1))) unsigned int*)g,
      (__attribute__((address_space(3))) unsigned int*)l, 16, 0, 0);
}

// raw workgroup barrier (no forced vmcnt(0) drain)
__device__ __forceinline__ void BARR() {
  asm volatile("" ::: "memory");
  __builtin_amdgcn_s_barrier();
  asm volatile("" ::: "memory");
}
#define VMCNT(n) asm volatile("s_waitcnt vmcnt(" #n ")" ::: "memory")
#define LGKM0 asm volatile("s_waitcnt lgkmcnt(0)" ::: "memory")
#define FENCE asm volatile("" ::: "memory")

// ---------------------------------------------------------------------------
// fp32 -> bf16 cast, WEIGHTS ONLY (X is consumed fp32 directly by qkv_f32a).
// 4M elems, 8/thread, 2048 blocks. ws: Wq 0 | Wk 1M | Wv 2M | Wo 3M (u16).
// ---------------------------------------------------------------------------
__global__ __launch_bounds__(256)
void cast_w(const float* __restrict__ wq, const float* __restrict__ wk,
            const float* __restrict__ wv, const float* __restrict__ wo,
            u16* __restrict__ ws) {
  const int i = (blockIdx.x * 256 + threadIdx.x) * 8;
  const int seg = i >> 20;
  const float* s =
      ((seg == 0) ? wq : (seg == 1) ? wk : (seg == 2) ? wv : wo) + (i & 1048575);
  float4 v0 = *(const float4*)s;
  float4 v1 = *(const float4*)(s + 4);
  u16x8 p = {f2bf(v0.x), f2bf(v0.y), f2bf(v0.z), f2bf(v0.w),
             f2bf(v1.x), f2bf(v1.y), f2bf(v1.z), f2bf(v1.w)};
  *(u16x8*)(ws + i) = p;
}

// ---------------------------------------------------------------------------
// QKV projection with FUSED fp32->bf16 on the A (X) operand.
// 128x128 tile, 4 waves, 64 KB LDS (2 blocks/CU), 2-phase counted-vmcnt.
// A: reg-staged (8x dwordx4 fp32 -> cvt -> 4x swizzled ds_write_b128),
//    issued 3 phases ahead into alternating rE/rO (static indexing, rule 20).
// B (weights, pre-cast bf16): global_load_lds, staged 1 tile ahead.
// Per K-tile t (buf = (t&1)*32KB):
//  ph1: STGB(t+1)->buf^1 | issue A-loads(t+2) | dsr A(8)+Blo(4) | 16 MFMA | bar
//  ph2: [auto-vmcnt] cvt+ds_write A(t+1)->buf^1 | dsr Bhi(4) | 16 MFMA
//       | vmcnt(8) [B(t+1) landed; A(t+2) 8 stay in flight] | lgkm(0) | bar
// Ledger: A-region of buf^1 last read ph1(t-1) [2 bars back]; B-region of
// buf^1 last read ph2(t-1) [1 bar back]. Reads of A(t+1)/B(t+1) in ph1(t+1)
// see ds_writes (lgkm0+bar) and retired gl16s (vmcnt(8)+bar). Tails:
// t=14 ph2 -> vmcnt(0) (no A(16) issued); t=15 ph2 -> no stage/write/waits.
// ---------------------------------------------------------------------------
__global__ __launch_bounds__(256)
void qkv_f32a(const float* __restrict__ Xq, const float* __restrict__ Xk,
              const float* __restrict__ Xv, const u16* __restrict__ Wall,
              const float* __restrict__ bq, const float* __restrict__ bk,
              const float* __restrict__ bv, u16* __restrict__ Qw,
              u16* __restrict__ Kw, u16* __restrict__ Vw) {
  const int bid = blockIdx.x;
  const int sw = (bid & 7) * 96 + (bid >> 3);  // XCD-contiguous, 768 % 8 == 0
  const int z = sw >> 8;
  const int rem = sw & 255;
  const int m0 = (rem >> 3) << 7, n0 = (rem & 7) << 7;

  const float* __restrict__ X = (z == 0) ? Xq : (z == 1) ? Xk : Xv;
  const u16* __restrict__ Wp = Wall + z * 1048576;
  const float* Bi = (z == 0) ? bq : (z == 1) ? bk : bv;
  u16* O = (z == 0) ? Qw : (z == 1) ? Kw : Vw;

  const int tid = threadIdx.x, lane = tid & 63, w = tid >> 6;
  const int wm = w >> 1, wn = w & 1;
  const int r = lane & 15, g = lane >> 4;

  __shared__ u16 SH[32768];  // 64 KB: per buf { A 16K | B 16K }
  char* sb = (char*)SH;

  f32x4 acc[4][4] = {};
  bf16x8 af[2][4], bf[2][4];
  float4 rE[8], rO[8];

  const int colr0 = (g * 16) ^ ((r & 7) << 4);
  const int colr1 = (64 + g * 16) ^ ((r & 7) << 4);
  const int rowAb = (wm * 64 + r) * 128;
  const int rowBb = 16384 + (wn * 64 + r) * 128;
  const int arow = tid >> 3;         // 0..31 (+c*32)
  const int acolb = (tid & 7) * 16;  // true byte col of this thread's 16B
  const int aswz = acolb ^ ((arow & 7) << 4);
  const float* Xbase = X + (m0 + arow) * 1024 + (tid & 7) * 8;

#define ISSUEA(regs, tt)                                                    \
  {                                                                         \
    FENCE;                                                                  \
    _Pragma("unroll") for (int c = 0; c < 4; ++c) {                         \
      const float* xp = Xbase + c * 32768 + (tt)*64;                        \
      regs[2 * c] = *(const float4*)xp;                                     \
      regs[2 * c + 1] = *(const float4*)(xp + 4);                           \
    }                                                                       \
    FENCE;                                                                  \
  }
#define WRITEA(regs, bufb)                                                  \
  _Pragma("unroll") for (int c = 0; c < 4; ++c) {                           \
    u16x8 pk = {f2bf(regs[2 * c].x),     f2bf(regs[2 * c].y),               \
                f2bf(regs[2 * c].z),     f2bf(regs[2 * c].w),               \
                f2bf(regs[2 * c + 1].x), f2bf(regs[2 * c + 1].y),           \
                f2bf(regs[2 * c + 1].z), f2bf(regs[2 * c + 1].w)};          \
    *(u16x8*)(sb + (bufb) + (c * 32 + arow) * 128 + aswz) = pk;             \
  }
#define QSTGB(tt)                                                           \
  {                                                                         \
    FENCE;                                                                  \
    _Pragma("unroll") for (int c = 0; c < 2; ++c)                           \
        _Pragma("unroll") for (int jj = 0; jj < 2; ++jj)                    \
            gl16(Wp + (n0 + c * 64 + (w << 4) + jj * 8 + (lane >> 3)) * 1024 + \
                     (tt)*64 + (((lane & 7) ^ (lane >> 3)) << 3),           \
                 (u16*)(sb + (((tt)&1) << 15) + 16384 + c * 8192 +          \
                        (w << 11) + (jj << 10)));                           \
    FENCE;                                                                  \
  }
#define QLDA(bo)                                                            \
  _Pragma("unroll") for (int m = 0; m < 4; ++m) {                           \
    char* p = sb + (bo) + rowAb + m * 16 * 128;                             \
    af[0][m] = __builtin_bit_cast(bf16x8, *(const u16x8*)(p + colr0));      \
    af[1][m] = __builtin_bit_cast(bf16x8, *(const u16x8*)(p + colr1));      \
  }
#define QLDB(bo, n)                                                         \
  {                                                                         \
    char* p = sb + (bo) + rowBb + (n)*16 * 128;                             \
    bf[0][n] = __builtin_bit_cast(bf16x8, *(const u16x8*)(p + colr0));      \
    bf[1][n] = __builtin_bit_cast(bf16x8, *(const u16x8*)(p + colr1));      \
  }
#define QFMA(nh)                                                            \
  __builtin_amdgcn_s_setprio(1);                                            \
  _Pragma("unroll") for (int m = 0; m < 4; ++m)                             \
  _Pragma("unroll") for (int n = 0; n < 2; ++n) {                           \
    acc[m][(nh)*2 + n] =                                                    \
        MFMA16(af[0][m], bf[0][(nh)*2 + n], acc[m][(nh)*2 + n], 0, 0, 0);   \
    acc[m][(nh)*2 + n] =                                                    \
        MFMA16(af[1][m], bf[1][(nh)*2 + n], acc[m][(nh)*2 + n], 0, 0, 0);   \
  }                                                                         \
  __builtin_amdgcn_s_setprio(0);

  // prologue: queue = A(0)[8] rE, B(0)[4], A(1)[8] rO
  ISSUEA(rE, 0);
  QSTGB(0);
  ISSUEA(rO, 1);
  WRITEA(rE, 0);  // compiler auto-waits rE's loads (vmcnt 12)
  VMCNT(8);       // B(0) landed; rO's 8 stay in flight
  LGKM0;
  __builtin_amdgcn_s_barrier();
  FENCE;

#pragma unroll 1
  for (int u = 0; u < 8; ++u) {
    const int t0 = 2 * u, t1 = 2 * u + 1;
    // ======== t0 (even, buf 0) ========
    // ph1
    if (t0 < 15) QSTGB(t0 + 1);
    if (t0 < 14) ISSUEA(rE, t0 + 2);
    QLDA(0);
    QLDB(0, 0);
    QLDB(0, 1);
    QFMA(0);
    BARR();
    // ph2
    if (t0 < 15) WRITEA(rO, 32768);  // A(t0+1) -> buf1 (auto-vmcnt for rO)
    QLDB(0, 2);
    QLDB(0, 3);
    QFMA(1);
    if (t0 < 14) { VMCNT(8); } else { VMCNT(0); }
    LGKM0;
    BARR();
    // ======== t1 (odd, buf 32768) ========
    // ph1
    if (t1 < 15) QSTGB(t1 + 1);
    if (t1 < 14) ISSUEA(rO, t1 + 2);
    QLDA(32768);
    QLDB(32768, 0);
    QLDB(32768, 1);
    QFMA(0);
    BARR();
    // ph2
    if (t1 < 15) WRITEA(rE, 0);  // A(t1+1) -> buf0
    QLDB(32768, 2);
    QLDB(32768, 3);
    QFMA(1);
    if (t1 < 14) { VMCNT(8); } else if (t1 == 14) { VMCNT(0); }
    if (t1 < 15) LGKM0;
    BARR();
  }

  // epilogue -> bf16 [B,H,S,64]; C/D layout col=lane&15, row=g*4+q
#pragma unroll
  for (int n = 0; n < 4; ++n) {
    const int gn = n0 + wn * 64 + n * 16 + r;
    const int hh = gn >> 6, d = gn & 63;
    const float bv = Bi[gn];
#pragma unroll
    for (int m = 0; m < 4; ++m) {
#pragma unroll
      for (int q = 0; q < 4; ++q) {
        int gm = m0 + wm * 64 + m * 16 + g * 4 + q;
        int bb = gm >> 11, sIdx = gm & 2047;
        O[((bb * 16 + hh) * 2048 + sIdx) * 64 + d] = f2bf(acc[m][n][q] + bv);
      }
    }
  }
#undef ISSUEA
#undef WRITEA
#undef QSTGB
#undef QLDA
#undef QLDB
#undef QFMA
}

// ---------------------------------------------------------------------------
// 128x128 2-phase counted-vmcnt GEMM core (round-4-proven) — for out proj.
// ---------------------------------------------------------------------------
#define OSTGA(tt, c, j)                                                     \
  gl16(Ain + (m0 + (c)*64 + (w << 4) + (j)*8 + (lane >> 3)) * 1024 +        \
           (tt)*64 + (((lane & 7) ^ (lane >> 3)) << 3),                     \
       (u16*)(sb + (((tt)&1) << 15) + (c)*8192 + (w << 11) + ((j) << 10)))
#define OSTGB(tt, c, j)                                                     \
  gl16(W + (n0 + (c)*64 + (w << 4) + (j)*8 + (lane >> 3)) * 1024 +          \
           (tt)*64 + (((lane & 7) ^ (lane >> 3)) << 3),                     \
       (u16*)(sb + (((tt)&1) << 15) + 16384 + (c)*8192 + (w << 11) +        \
              ((j) << 10)))
#define OLDA()                                                              \
  _Pragma("unroll") for (int m = 0; m < 4; ++m) {                           \
    char* p = sb + bo + rowAb + m * 16 * 128;                               \
    af[0][m] = __builtin_bit_cast(bf16x8, *(const u16x8*)(p + colr0));      \
    af[1][m] = __builtin_bit_cast(bf16x8, *(const u16x8*)(p + colr1));      \
  }
#define OLDB(n)                                                             \
  {                                                                         \
    char* p = sb + bo + rowBb + (n)*16 * 128;                               \
    bf[0][n] = __builtin_bit_cast(bf16x8, *(const u16x8*)(p + colr0));      \
    bf[1][n] = __builtin_bit_cast(bf16x8, *(const u16x8*)(p + colr1));      \
  }
#define OFMA(nh)                                                            \
  __builtin_amdgcn_s_setprio(1);                                            \
  _Pragma("unroll") for (int m = 0; m < 4; ++m)                             \
  _Pragma("unroll") for (int n = 0; n < 2; ++n) {                           \
    acc[m][(nh)*2 + n] =                                                    \
        MFMA16(af[0][m], bf[0][(nh)*2 + n], acc[m][(nh)*2 + n], 0, 0, 0);   \
    acc[m][(nh)*2 + n] =                                                    \
        MFMA16(af[1][m], bf[1][(nh)*2 + n], acc[m][(nh)*2 + n], 0, 0, 0);   \
  }                                                                         \
  __builtin_amdgcn_s_setprio(0);

__device__ __forceinline__ void core128(const u16* __restrict__ Ain,
                                        const u16* __restrict__ W, int m0,
                                        int n0, char* sb,
                                        f32x4 (&acc)[4][4]) {
  const int tid = threadIdx.x, lane = tid & 63, w = tid >> 6;
  const int wm = w >> 1, wn = w & 1;
  const int r = lane & 15, g = lane >> 4;
  bf16x8 af[2][4], bf[2][4];

  const int colr0 = (g * 16) ^ ((r & 7) << 4);
  const int colr1 = (64 + g * 16) ^ ((r & 7) << 4);
  const int rowAb = (wm * 64 + r) * 128;
  const int rowBb = 16384 + (wn * 64 + r) * 128;

#pragma unroll
  for (int c = 0; c < 2; ++c) { OSTGA(0, c, 0); OSTGA(0, c, 1); }
#pragma unroll
  for (int c = 0; c < 2; ++c) { OSTGB(0, c, 0); OSTGB(0, c, 1); }
#pragma unroll
  for (int c = 0; c < 2; ++c) { OSTGA(1, c, 0); OSTGA(1, c, 1); }
  VMCNT(4);
  __builtin_amdgcn_s_barrier();
  asm volatile("" ::: "memory");

  for (int t = 0; t < 16; ++t) {
    const int bo = (t & 1) << 15;
    if (t < 15) { OSTGB(t + 1, 0, 0); OSTGB(t + 1, 0, 1); OSTGB(t + 1, 1, 0); OSTGB(t + 1, 1, 1); }
    OLDA();
    OLDB(0); OLDB(1);
    OFMA(0);
    BARR();
    if (t < 14) { OSTGA(t + 2, 0, 0); OSTGA(t + 2, 0, 1); OSTGA(t + 2, 1, 0); OSTGA(t + 2, 1, 1); }
    OLDB(2); OLDB(3);
    OFMA(1);
    if (t < 14) { VMCNT(4); } else if (t == 14) { VMCNT(0); }
    BARR();
  }
}

__global__ __launch_bounds__(256)
void out_gemm_p(const u16* __restrict__ Ain2, const u16* __restrict__ W2,
                const float* __restrict__ Bi, float* __restrict__ C) {
  const int bid = blockIdx.x;
  const int s = (bid & 7) * 32 + (bid >> 3);  // 256 % 8 == 0
  const int m0 = (s >> 3) << 7, n0 = (s & 7) << 7;

  const int tid = threadIdx.x, lane = tid & 63, w = tid >> 6;
  const int wm = w >> 1, wn = w & 1;
  const int r = lane & 15, g = lane >> 4;

  __shared__ u16 SH[32768];  // 64 KB
  f32x4 acc[4][4] = {};
  core128(Ain2, W2, m0, n0, (char*)SH, acc);

#pragma unroll
  for (int m = 0; m < 4; ++m) {
#pragma unroll
    for (int n = 0; n < 4; ++n) {
      int gn = n0 + wn * 64 + n * 16 + r;
      float bv = Bi[gn];
#pragma unroll
      for (int q = 0; q < 4; ++q) {
        int gm = m0 + wm * 64 + m * 16 + g * 4 + q;
        C[gm * 1024 + gn] = acc[m][n][q] + bv;
      }
    }
  }
}

// ---------------------------------------------------------------------------
// Sparse flash attention (unchanged). grid (32, 16, 2), 256 threads.
// ---------------------------------------------------------------------------
__global__ __launch_bounds__(256)
void attn_kernel(const u16* __restrict__ Q, const u16* __restrict__ K,
                 const u16* __restrict__ V, u16* __restrict__ O) {
  const int qt = blockIdx.x, h = blockIdx.y, b = blockIdx.z;
  const int tid = threadIdx.x, lane = tid & 63, w = tid >> 6;
  const int r = lane & 15, g = lane >> 4;
  const int q0 = qt * 64;
  const int base = (b * 16 + h) * 131072;
  const u16* Qb = Q + base;
  const u16* Kb = K + base;
  const u16* Vb = V + base;

  __shared__ u16 Ks[64 * 64];
  __shared__ u16 Vt[64 * 64];
  __shared__ u16 Pl[4608];

  bf16x8 qf[2];
  {
    const u16* qp = Qb + (q0 + w * 16 + r) * 64 + g * 8;
    qf[0] = __builtin_bit_cast(bf16x8, *(const u16x8*)qp);
    qf[1] = __builtin_bit_cast(bf16x8, *(const u16x8*)(qp + 32));
  }

  f32x4 acc[4] = {};
  float m_run[4] = {-1e30f, -1e30f, -1e30f, -1e30f};
  float l_run[4] = {};

  const int nt = (qt <= 3) ? (qt + 1) : 4;
  const int srow = tid >> 3, sc = (tid & 7) * 8;

  for (int tix = 0; tix < nt; ++tix) {
    const int t = (tix == 0) ? 0 : ((qt <= 3) ? tix : (qt - 3 + tix));
    const int j0 = t * 64;
    __syncthreads();
#pragma unroll
    for (int i = 0; i < 2; ++i) {
      int row = i * 32 + srow;
      u16x8 kv = *(const u16x8*)(Kb + (j0 + row) * 64 + sc);
      *(u16x8*)((char*)Ks + swz(row, sc * 2)) = kv;
      u16x8 vv = *(const u16x8*)(Vb + (j0 + row) * 64 + sc);
#pragma unroll
      for (int qq = 0; qq < 8; ++qq) {
        int d = sc + qq;
        *(u16*)((char*)Vt + d * 128 + ((2 * row) ^ ((d & 7) << 4))) = vv[qq];
      }
    }
    __syncthreads();

    f32x4 S[4] = {};
#pragma unroll
    for (int kk = 0; kk < 2; ++kk)
#pragma unroll
      for (int n = 0; n < 4; ++n) {
        bf16x8 kf = __builtin_bit_cast(
            bf16x8,
            *(const u16x8*)((char*)Ks + swz(n * 16 + r, kk * 64 + g * 16)));
        S[n] = MFMA16(qf[kk], kf, S[n], 0, 0, 0);
      }

    float mloc[4] = {-1e30f, -1e30f, -1e30f, -1e30f};
#pragma unroll
    for (int n = 0; n < 4; ++n) {
      int j = j0 + n * 16 + r;
#pragma unroll
      for (int q = 0; q < 4; ++q) {
        int i = q0 + w * 16 + g * 4 + q;
        bool ok = (j <= i) && (((i - j) <= 128) || (j < 16));
        float s = ok ? S[n][q] * 0.125f : -1e30f;
        S[n][q] = s;
        mloc[q] = fmaxf(mloc[q], s);
      }
    }
#pragma unroll
    for (int q = 0; q < 4; ++q)
#pragma unroll
      for (int off = 1; off < 16; off <<= 1)
        mloc[q] = fmaxf(mloc[q], __shfl_xor(mloc[q], off));

    float alpha[4], rsum[4] = {};
#pragma unroll
    for (int q = 0; q < 4; ++q) {
      float mn = fmaxf(m_run[q], mloc[q]);
      alpha[q] = __expf(m_run[q] - mn);
      m_run[q] = mn;
    }
#pragma unroll
    for (int n = 0; n < 4; ++n)
#pragma unroll
      for (int q = 0; q < 4; ++q) {
        float p = __expf(S[n][q] - m_run[q]);
        S[n][q] = p;
        rsum[q] += p;
      }
#pragma unroll
    for (int q = 0; q < 4; ++q) {
#pragma unroll
      for (int off = 1; off < 16; off <<= 1)
        rsum[q] += __shfl_xor(rsum[q], off);
      l_run[q] = l_run[q] * alpha[q] + rsum[q];
    }
#pragma unroll
    for (int n = 0; n < 4; ++n) {
      acc[n][0] *= alpha[0];
      acc[n][1] *= alpha[1];
      acc[n][2] *= alpha[2];
      acc[n][3] *= alpha[3];
    }

#pragma unroll
    for (int n = 0; n < 4; ++n)
#pragma unroll
      for (int q = 0; q < 4; ++q)
        *((u16*)((char*)Pl + w * 2304 + (g * 4 + q) * 144) + (n * 16 + r)) =
            f2bf(S[n][q]);

#pragma unroll
    for (int kk = 0; kk < 2; ++kk) {
      bf16x8 pf = __builtin_bit_cast(
          bf16x8,
          *(const u16x8*)((char*)Pl + w * 2304 + r * 144 + kk * 64 + g * 16));
#pragma unroll
      for (int n = 0; n < 4; ++n) {
        bf16x8 vf = __builtin_bit_cast(
            bf16x8,
            *(const u16x8*)((char*)Vt + swz(n * 16 + r, kk * 64 + g * 16)));
        acc[n] = MFMA16(pf, vf, acc[n], 0, 0, 0);
      }
    }
  }

#pragma unroll
  for (int n = 0; n < 4; ++n)
#pragma unroll
    for (int q = 0; q < 4; ++q) {
      int s = q0 + w * 16 + g * 4 + q;
      int d = n * 16 + r;
      O[(b * 2048 + s) * 1024 + h * 64 + d] = f2bf(acc[n][q] / l_run[q]);
    }
}

// ---------------------------------------------------------------------------
extern "C" void kernel_launch(void* const* d_in, const int* in_sizes, int n_in,
                              void* d_out, int out_size, void* d_ws,
                              size_t ws_size, hipStream_t stream) {
  const float* query = (const float*)d_in[0];
  const float* key = (const float*)d_in[1];
  const float* value = (const float*)d_in[2];
  const float* b_q = (const float*)d_in[4];
  const float* b_k = (const float*)d_in[6];
  const float* b_v = (const float*)d_in[8];
  const float* b_o = (const float*)d_in[10];

  u16* ws = (u16*)d_ws;
  // ws (u16): Wq 0 | Wk 1M | Wv 2M | Wo 3M | Qw 4M | Kw 8M | Vw 12M | Aw 16M
  u16* Qw = ws + 4194304;
  u16* Kw = ws + 8388608;
  u16* Vw = ws + 12582912;
  u16* Aw = ws + 16777216;

  cast_w<<<dim3(2048), dim3(256), 0, stream>>>(
      (const float*)d_in[3], (const float*)d_in[5], (const float*)d_in[7],
      (const float*)d_in[9], ws);
  qkv_f32a<<<dim3(768), dim3(256), 0, stream>>>(query, key, value, ws, b_q,
                                                b_k, b_v, Qw, Kw, Vw);
  attn_kernel<<<dim3(32, 16, 2), dim3(256), 0, stream>>>(Qw, Kw, Vw, Aw);
  out_gemm_p<<<dim3(256), dim3(256), 0, stream>>>(Aw, ws + 3145728, b_o,
                                                  (float*)d_out);
}

// Round 8
// 92.720 us; speedup vs baseline: 1.1210x; 1.1210x over previous
//
#include <hip/hip_runtime.h>

typedef unsigned short u16;
typedef u16 u16x8 __attribute__((ext_vector_type(8)));
typedef __bf16 bf16x8 __attribute__((ext_vector_type(8)));
typedef float f32x4 __attribute__((ext_vector_type(4)));

#define MFMA16 __builtin_amdgcn_mfma_f32_16x16x32_bf16

__device__ __forceinline__ u16 f2bf(float f) {
  unsigned u = __builtin_bit_cast(unsigned, f);
  u += 0x7FFFu + ((u >> 16) & 1u);
  return (u16)(u >> 16);
}

// XOR-swizzled LDS byte address for 64-bf16 (128B) rows (guide G4).
__device__ __forceinline__ int swz(int row, int bcol) {
  return row * 128 + (bcol ^ ((row & 7) << 4));
}

__device__ __forceinline__ void gl16(const u16* g, u16* l) {
  __builtin_amdgcn_global_load_lds(
      (const __attribute__((address_space(1))) unsigned int*)g,
      (__attribute__((address_space(3))) unsigned int*)l, 16, 0, 0);
}

// raw workgroup barrier (no forced vmcnt(0) drain)
__device__ __forceinline__ void BARR() {
  asm volatile("" ::: "memory");
  __builtin_amdgcn_s_barrier();
  asm volatile("" ::: "memory");
}
#define VMCNT(n) asm volatile("s_waitcnt vmcnt(" #n ")" ::: "memory")
#define LGKM0 asm volatile("s_waitcnt lgkmcnt(0)" ::: "memory")

// ---------------------------------------------------------------------------
// Flattened fp32 -> bf16 cast. 16M elements total, 8/thread, 8192 blocks.
// ws layout (u16): Wq 0 | Wk 1M | Wv 2M | Wo 3M | Xq 4M | Xk 8M | Xv 12M
// ---------------------------------------------------------------------------
__global__ __launch_bounds__(256)
void cast_all(const float* __restrict__ q, const float* __restrict__ k,
              const float* __restrict__ v, const float* __restrict__ wq,
              const float* __restrict__ wk, const float* __restrict__ wv,
              const float* __restrict__ wo, u16* __restrict__ ws) {
  const long i = ((long)blockIdx.x * 256 + threadIdx.x) * 8;
  const float* s;
  u16* d;
  if (i < 12582912) {  // X region (12M)
    const int seg = (int)(i >> 22);
    const float* xs = (seg == 0) ? q : (seg == 1) ? k : v;
    s = xs + (i & 4194303);
    d = ws + 4194304 + i;
  } else {  // weights (4M)
    const long j = i - 12582912;
    const int seg = (int)(j >> 20);
    const float* wsrc = (seg == 0) ? wq : (seg == 1) ? wk : (seg == 2) ? wv : wo;
    s = wsrc + (j & 1048575);
    d = ws + j;
  }
  float4 v0 = *(const float4*)s;
  float4 v1 = *(const float4*)(s + 4);
  u16x8 p = {f2bf(v0.x), f2bf(v0.y), f2bf(v0.z), f2bf(v0.w),
             f2bf(v1.x), f2bf(v1.y), f2bf(v1.z), f2bf(v1.w)};
  *(u16x8*)d = p;
}

// ---------------------------------------------------------------------------
// Shared 128x128 2-phase counted-vmcnt GEMM core (round-4/5-proven).
// ---------------------------------------------------------------------------
#define OSTGA(tt, c, j)                                                     \
  gl16(Ain + (m0 + (c)*64 + (w << 4) + (j)*8 + (lane >> 3)) * 1024 +        \
           (tt)*64 + (((lane & 7) ^ (lane >> 3)) << 3),                     \
       (u16*)(sb + (((tt)&1) << 15) + (c)*8192 + (w << 11) + ((j) << 10)))
#define OSTGB(tt, c, j)                                                     \
  gl16(W + (n0 + (c)*64 + (w << 4) + (j)*8 + (lane >> 3)) * 1024 +          \
           (tt)*64 + (((lane & 7) ^ (lane >> 3)) << 3),                     \
       (u16*)(sb + (((tt)&1) << 15) + 16384 + (c)*8192 + (w << 11) +        \
              ((j) << 10)))
#define OLDA()                                                              \
  _Pragma("unroll") for (int m = 0; m < 4; ++m) {                           \
    char* p = sb + bo + rowAb + m * 16 * 128;                               \
    af[0][m] = __builtin_bit_cast(bf16x8, *(const u16x8*)(p + colr0));      \
    af[1][m] = __builtin_bit_cast(bf16x8, *(const u16x8*)(p + colr1));      \
  }
#define OLDB(n)                                                             \
  {                                                                         \
    char* p = sb + bo + rowBb + (n)*16 * 128;                               \
    bf[0][n] = __builtin_bit_cast(bf16x8, *(const u16x8*)(p + colr0));      \
    bf[1][n] = __builtin_bit_cast(bf16x8, *(const u16x8*)(p + colr1));      \
  }
#define OFMA(nh)                                                            \
  __builtin_amdgcn_s_setprio(1);                                            \
  _Pragma("unroll") for (int m = 0; m < 4; ++m)                             \
  _Pragma("unroll") for (int n = 0; n < 2; ++n) {                           \
    acc[m][(nh)*2 + n] =                                                    \
        MFMA16(af[0][m], bf[0][(nh)*2 + n], acc[m][(nh)*2 + n], 0, 0, 0);   \
    acc[m][(nh)*2 + n] =                                                    \
        MFMA16(af[1][m], bf[1][(nh)*2 + n], acc[m][(nh)*2 + n], 0, 0, 0);   \
  }                                                                         \
  __builtin_amdgcn_s_setprio(0);

__device__ __forceinline__ void core128(const u16* __restrict__ Ain,
                                        const u16* __restrict__ W, int m0,
                                        int n0, char* sb,
                                        f32x4 (&acc)[4][4]) {
  const int tid = threadIdx.x, lane = tid & 63, w = tid >> 6;
  const int wm = w >> 1, wn = w & 1;
  const int r = lane & 15, g = lane >> 4;
  bf16x8 af[2][4], bf[2][4];

  const int colr0 = (g * 16) ^ ((r & 7) << 4);
  const int colr1 = (64 + g * 16) ^ ((r & 7) << 4);
  const int rowAb = (wm * 64 + r) * 128;
  const int rowBb = 16384 + (wn * 64 + r) * 128;

#pragma unroll
  for (int c = 0; c < 2; ++c) { OSTGA(0, c, 0); OSTGA(0, c, 1); }
#pragma unroll
  for (int c = 0; c < 2; ++c) { OSTGB(0, c, 0); OSTGB(0, c, 1); }
#pragma unroll
  for (int c = 0; c < 2; ++c) { OSTGA(1, c, 0); OSTGA(1, c, 1); }
  VMCNT(4);
  __builtin_amdgcn_s_barrier();
  asm volatile("" ::: "memory");

  for (int t = 0; t < 16; ++t) {
    const int bo = (t & 1) << 15;
    if (t < 15) { OSTGB(t + 1, 0, 0); OSTGB(t + 1, 0, 1); OSTGB(t + 1, 1, 0); OSTGB(t + 1, 1, 1); }
    OLDA();
    OLDB(0); OLDB(1);
    OFMA(0);
    BARR();
    if (t < 14) { OSTGA(t + 2, 0, 0); OSTGA(t + 2, 0, 1); OSTGA(t + 2, 1, 0); OSTGA(t + 2, 1, 1); }
    OLDB(2); OLDB(3);
    OFMA(1);
    if (t < 14) { VMCNT(4); } else if (t == 14) { VMCNT(0); }
    BARR();
  }
}

// ---------------------------------------------------------------------------
// QKV projection: 768 blocks (3 z * 32 m * 8 n), 128x128 tile, 2 blocks/CU.
// ---------------------------------------------------------------------------
__global__ __launch_bounds__(256)
void qkv_gemm128(const u16* __restrict__ ws_in, const float* __restrict__ c0,
                 const float* __restrict__ c1, const float* __restrict__ c2,
                 u16* __restrict__ o0, u16* __restrict__ o1,
                 u16* __restrict__ o2) {
  const int bid = blockIdx.x;
  const int s = (bid & 7) * 96 + (bid >> 3);  // XCD-contiguous, 768 % 8 == 0
  const int z = s >> 8;
  const int rem = s & 255;
  const int m0 = (rem >> 3) << 7, n0 = (rem & 7) << 7;

  const u16* __restrict__ Ain = ws_in + 4194304 + z * 4194304;
  const u16* __restrict__ W = ws_in + z * 1048576;
  const float* Bi = (z == 0) ? c0 : (z == 1) ? c1 : c2;
  u16* O = (z == 0) ? o0 : (z == 1) ? o1 : o2;

  const int tid = threadIdx.x, lane = tid & 63, w = tid >> 6;
  const int wm = w >> 1, wn = w & 1;
  const int r = lane & 15, g = lane >> 4;

  __shared__ u16 SH[32768];  // 64 KB
  f32x4 acc[4][4] = {};
  core128(Ain, W, m0, n0, (char*)SH, acc);

  // epilogue -> bf16 [B,H,S,64]; C/D layout col=lane&15, row=g*4+q
#pragma unroll
  for (int n = 0; n < 4; ++n) {
    const int gn = n0 + wn * 64 + n * 16 + r;
    const int hh = gn >> 6, d = gn & 63;
    const float bv = Bi[gn];
#pragma unroll
    for (int m = 0; m < 4; ++m) {
#pragma unroll
      for (int q = 0; q < 4; ++q) {
        int gm = m0 + wm * 64 + m * 16 + g * 4 + q;
        int bb = gm >> 11, sIdx = gm & 2047;
        O[((bb * 16 + hh) * 2048 + sIdx) * 64 + d] = f2bf(acc[m][n][q] + bv);
      }
    }
  }
}

// ---------------------------------------------------------------------------
// Output projection: 256 blocks, 128x128 tile, fp32 out.
// ---------------------------------------------------------------------------
__global__ __launch_bounds__(256)
void out_gemm_p(const u16* __restrict__ Ain2, const u16* __restrict__ W2,
                const float* __restrict__ Bi, float* __restrict__ C) {
  const int bid = blockIdx.x;
  const int s = (bid & 7) * 32 + (bid >> 3);  // 256 % 8 == 0
  const int m0 = (s >> 3) << 7, n0 = (s & 7) << 7;

  const int tid = threadIdx.x, lane = tid & 63, w = tid >> 6;
  const int wm = w >> 1, wn = w & 1;
  const int r = lane & 15, g = lane >> 4;

  __shared__ u16 SH[32768];  // 64 KB
  f32x4 acc[4][4] = {};
  core128(Ain2, W2, m0, n0, (char*)SH, acc);

#pragma unroll
  for (int m = 0; m < 4; ++m) {
#pragma unroll
    for (int n = 0; n < 4; ++n) {
      int gn = n0 + wn * 64 + n * 16 + r;
      float bv = Bi[gn];
#pragma unroll
      for (int q = 0; q < 4; ++q) {
        int gm = m0 + wm * 64 + m * 16 + g * 4 + q;
        C[gm * 1024 + gn] = acc[m][n][q] + bv;
      }
    }
  }
}

// ---------------------------------------------------------------------------
// Sparse flash attention, T14 async-stage + double-buffered K/V.
// grid (32 qtiles, 16 heads, 2 batch), 256 threads (4 waves x 16 q-rows).
// Tiles per q-tile: {0} ∪ {qt-2, qt-1, qt}. Mask: j<=i && (i-j<=128 || j<16).
// Per tile tix (buf = tix&1):
//   write reg-staged K(swizzled vec) + V(transposed scatter) -> buf
//   issue next tile's K/V global loads into the OTHER reg set (in flight
//     across the barrier; retired by compiler auto-vmcnt at next write)
//   lgkmcnt(0); s_barrier   (ONE raw barrier/tile; no vmcnt drain)
//   compute QK^T / online softmax / PV on buf
// WAR ledger: buf b written at tix is last read at tix-2, two barriers back;
// write(b) concurrent with other waves' reads(b^1) touch disjoint halves.
// ---------------------------------------------------------------------------
__global__ __launch_bounds__(256)
void attn_kernel(const u16* __restrict__ Q, const u16* __restrict__ K,
                 const u16* __restrict__ V, u16* __restrict__ O) {
  const int qt = blockIdx.x, h = blockIdx.y, b = blockIdx.z;
  const int tid = threadIdx.x, lane = tid & 63, w = tid >> 6;
  const int r = lane & 15, g = lane >> 4;
  const int q0 = qt * 64;
  const int base = (b * 16 + h) * 131072;
  const u16* Qb = Q + base;

  __shared__ u16 Ks[2][4096];
  __shared__ u16 Vt[2][4096];  // transposed: Vt[d][j]
  __shared__ u16 Pl[4608];     // 4 waves x 16 rows x 144B stride

  bf16x8 qf[2];
  {
    const u16* qp = Qb + (q0 + w * 16 + r) * 64 + g * 8;
    qf[0] = __builtin_bit_cast(bf16x8, *(const u16x8*)qp);
    qf[1] = __builtin_bit_cast(bf16x8, *(const u16x8*)(qp + 32));
  }

  f32x4 acc[4] = {};
  float m_run[4] = {-1e30f, -1e30f, -1e30f, -1e30f};
  float l_run[4] = {};

  const int nt = (qt <= 3) ? (qt + 1) : 4;
  const int srow = tid >> 3, sc = (tid & 7) * 8;
  const u16* Kg = K + base + srow * 64 + sc;
  const u16* Vg = V + base + srow * 64 + sc;

  u16x8 krA[2], vrA[2], krB[2], vrB[2];
  // prologue: tile 0 (j0 = 0) into A regs
  krA[0] = *(const u16x8*)(Kg);
  krA[1] = *(const u16x8*)(Kg + 2048);
  vrA[0] = *(const u16x8*)(Vg);
  vrA[1] = *(const u16x8*)(Vg + 2048);

#pragma unroll
  for (int tix = 0; tix < 4; ++tix) {
    if (tix < nt) {
      const int j0 = ((tix == 0) ? 0 : ((qt <= 3) ? tix : (qt - 3 + tix))) * 64;
      const int bo = (tix & 1) * 8192;  // byte offset into Ks/Vt
      // ---- write staged regs -> LDS buf (auto-vmcnt retires their loads)
      if ((tix & 1) == 0) {
#pragma unroll
        for (int i = 0; i < 2; ++i) {
          int row = i * 32 + srow;
          *(u16x8*)((char*)Ks + bo + swz(row, sc * 2)) = krA[i];
#pragma unroll
          for (int qq = 0; qq < 8; ++qq) {
            int d = sc + qq;
            *(u16*)((char*)Vt + bo + d * 128 + ((2 * row) ^ ((d & 7) << 4))) =
                vrA[i][qq];
          }
        }
      } else {
#pragma unroll
        for (int i = 0; i < 2; ++i) {
          int row = i * 32 + srow;
          *(u16x8*)((char*)Ks + bo + swz(row, sc * 2)) = krB[i];
#pragma unroll
          for (int qq = 0; qq < 8; ++qq) {
            int d = sc + qq;
            *(u16*)((char*)Vt + bo + d * 128 + ((2 * row) ^ ((d & 7) << 4))) =
                vrB[i][qq];
          }
        }
      }
      // ---- prefetch next tile into the other reg set (stays in flight)
      if (tix + 1 < nt) {
        const int jn = (((qt <= 3) ? (tix + 1) : (qt - 2 + tix)) * 64) * 64;
        if ((tix & 1) == 0) {
          krB[0] = *(const u16x8*)(Kg + jn);
          krB[1] = *(const u16x8*)(Kg + jn + 2048);
          vrB[0] = *(const u16x8*)(Vg + jn);
          vrB[1] = *(const u16x8*)(Vg + jn + 2048);
        } else {
          krA[0] = *(const u16x8*)(Kg + jn);
          krA[1] = *(const u16x8*)(Kg + jn + 2048);
          vrA[0] = *(const u16x8*)(Vg + jn);
          vrA[1] = *(const u16x8*)(Vg + jn + 2048);
        }
      }
      LGKM0;
      BARR();

      // ---- S = Q K^T on buf
      f32x4 S[4] = {};
#pragma unroll
      for (int kk = 0; kk < 2; ++kk)
#pragma unroll
        for (int n = 0; n < 4; ++n) {
          bf16x8 kf = __builtin_bit_cast(
              bf16x8, *(const u16x8*)((char*)Ks + bo +
                                      swz(n * 16 + r, kk * 64 + g * 16)));
          S[n] = MFMA16(qf[kk], kf, S[n], 0, 0, 0);
        }

      float mloc[4] = {-1e30f, -1e30f, -1e30f, -1e30f};
#pragma unroll
      for (int n = 0; n < 4; ++n) {
        int j = j0 + n * 16 + r;
#pragma unroll
        for (int q = 0; q < 4; ++q) {
          int i = q0 + w * 16 + g * 4 + q;
          bool ok = (j <= i) && (((i - j) <= 128) || (j < 16));
          float s = ok ? S[n][q] * 0.125f : -1e30f;
          S[n][q] = s;
          mloc[q] = fmaxf(mloc[q], s);
        }
      }
#pragma unroll
      for (int q = 0; q < 4; ++q)
#pragma unroll
        for (int off = 1; off < 16; off <<= 1)
          mloc[q] = fmaxf(mloc[q], __shfl_xor(mloc[q], off));

      float alpha[4], rsum[4] = {};
#pragma unroll
      for (int q = 0; q < 4; ++q) {
        float mn = fmaxf(m_run[q], mloc[q]);
        alpha[q] = __expf(m_run[q] - mn);
        m_run[q] = mn;
      }
#pragma unroll
      for (int n = 0; n < 4; ++n)
#pragma unroll
        for (int q = 0; q < 4; ++q) {
          float p = __expf(S[n][q] - m_run[q]);
          S[n][q] = p;
          rsum[q] += p;
        }
#pragma unroll
      for (int q = 0; q < 4; ++q) {
#pragma unroll
        for (int off = 1; off < 16; off <<= 1)
          rsum[q] += __shfl_xor(rsum[q], off);
        l_run[q] = l_run[q] * alpha[q] + rsum[q];
      }
#pragma unroll
      for (int n = 0; n < 4; ++n) {
        acc[n][0] *= alpha[0];
        acc[n][1] *= alpha[1];
        acc[n][2] *= alpha[2];
        acc[n][3] *= alpha[3];
      }

      // P (bf16) -> per-wave LDS staging (w-private; lgkm auto-waited)
#pragma unroll
      for (int n = 0; n < 4; ++n)
#pragma unroll
        for (int q = 0; q < 4; ++q)
          *((u16*)((char*)Pl + w * 2304 + (g * 4 + q) * 144) + (n * 16 + r)) =
              f2bf(S[n][q]);

#pragma unroll
      for (int kk = 0; kk < 2; ++kk) {
        bf16x8 pf = __builtin_bit_cast(
            bf16x8, *(const u16x8*)((char*)Pl + w * 2304 + r * 144 + kk * 64 +
                                    g * 16));
#pragma unroll
        for (int n = 0; n < 4; ++n) {
          bf16x8 vf = __builtin_bit_cast(
              bf16x8, *(const u16x8*)((char*)Vt + bo +
                                      swz(n * 16 + r, kk * 64 + g * 16)));
          acc[n] = MFMA16(pf, vf, acc[n], 0, 0, 0);
        }
      }
    }
  }

#pragma unroll
  for (int n = 0; n < 4; ++n)
#pragma unroll
    for (int q = 0; q < 4; ++q) {
      int s = q0 + w * 16 + g * 4 + q;
      int d = n * 16 + r;
      O[(b * 2048 + s) * 1024 + h * 64 + d] = f2bf(acc[n][q] / l_run[q]);
    }
}

// ---------------------------------------------------------------------------
extern "C" void kernel_launch(void* const* d_in, const int* in_sizes, int n_in,
                              void* d_out, int out_size, void* d_ws,
                              size_t ws_size, hipStream_t stream) {
  const float* b_q = (const float*)d_in[4];
  const float* b_k = (const float*)d_in[6];
  const float* b_v = (const float*)d_in[8];
  const float* b_o = (const float*)d_in[10];

  u16* ws = (u16*)d_ws;
  // ws (u16): Wq 0 | Wk 1M | Wv 2M | Wo 3M | Xq 4M | Xk 8M | Xv 12M |
  //           Qw 16M | Kw 20M | Vw 24M | Aw aliases Xq (4M)
  u16* Qw = ws + 16777216;
  u16* Kw = ws + 20971520;
  u16* Vw = ws + 25165824;
  u16* Aw = ws + 4194304;  // aliases Xq (dead after qkv projection)

  cast_all<<<dim3(8192), dim3(256), 0, stream>>>(
      (const float*)d_in[0], (const float*)d_in[1], (const float*)d_in[2],
      (const float*)d_in[3], (const float*)d_in[5], (const float*)d_in[7],
      (const float*)d_in[9], ws);
  qkv_gemm128<<<dim3(768), dim3(256), 0, stream>>>(ws, b_q, b_k, b_v, Qw, Kw,
                                                   Vw);
  attn_kernel<<<dim3(32, 16, 2), dim3(256), 0, stream>>>(Qw, Kw, Vw, Aw);
  out_gemm_p<<<dim3(256), dim3(256), 0, stream>>>(Aw, ws + 3145728, b_o,
                                                  (float*)d_out);
}